// Round 13
// baseline (105.214 us; speedup 1.0000x reference)
//
#include <hip/hip_runtime.h>

#define HSZ 4096
#define BSZ 4096
#define PSZ 512
#define NB1 512    // k1 blocks, 8 rows each

// ws layout (fast path):
// [0, 16384)        colsum    float[4096]  (memset 0 each call)
// [16384, 18432)    blocknorm float[512]
// fallback path reuses [0,33KB) as before
#define WS_NEEDED 33000ull

__device__ __forceinline__ unsigned ford(float f) {
    unsigned b = __float_as_uint(f);
    return b ^ ((b & 0x80000000u) ? 0xFFFFFFFFu : 0x80000000u);
}

// streams x once: blocknorm (row L2 norms) + direct atomic column sums
__global__ __launch_bounds__(256, 2) void k1_reduce(const float* __restrict__ x,
                                                    float* __restrict__ colsum,
                                                    float* __restrict__ blocknorm) {
    const int tid = threadIdx.x;
    const int b = blockIdx.x;

    const int r0 = b * 8;
    float4 c0 = {0,0,0,0}, c1 = {0,0,0,0}, c2 = {0,0,0,0}, c3 = {0,0,0,0};
    __shared__ float sq[8][256];
    __shared__ float norm8[8];

    #pragma unroll
    for (int r = 0; r < 8; ++r) {
        const float4* row = (const float4*)(x + (size_t)(r0 + r) * HSZ);
        float4 a = row[tid];
        float4 e = row[256 + tid];
        float4 c = row[512 + tid];
        float4 d = row[768 + tid];
        c0.x += a.x; c0.y += a.y; c0.z += a.z; c0.w += a.w;
        c1.x += e.x; c1.y += e.y; c1.z += e.z; c1.w += e.w;
        c2.x += c.x; c2.y += c.y; c2.z += c.z; c2.w += c.w;
        c3.x += d.x; c3.y += d.y; c3.z += d.z; c3.w += d.w;
        sq[r][tid] = a.x*a.x + a.y*a.y + a.z*a.z + a.w*a.w
                   + e.x*e.x + e.y*e.y + e.z*e.z + e.w*e.w
                   + c.x*c.x + c.y*c.y + c.z*c.z + c.w*c.w
                   + d.x*d.x + d.y*d.y + d.z*d.z + d.w*d.w;
    }
    __syncthreads();
    {
        const int w = tid >> 6;
        const int l = tid & 63;
        #pragma unroll
        for (int rr = 2 * w; rr <= 2 * w + 1; ++rr) {
            float s = sq[rr][l] + sq[rr][64 + l] + sq[rr][128 + l] + sq[rr][192 + l];
            #pragma unroll
            for (int m = 1; m <= 32; m <<= 1) s += __shfl_xor(s, m);
            if (l == 0) norm8[rr] = sqrtf(s);
        }
    }
    __syncthreads();
    if (tid == 0) {
        float s = 0.f;
        #pragma unroll
        for (int i = 0; i < 8; ++i) s += norm8[i];
        blocknorm[b] = s;
    }

    // direct atomic column-sum accumulation (replaces colpartial + k2)
    const int cb = 4 * tid;
    atomicAdd(&colsum[cb + 0],        c0.x); atomicAdd(&colsum[cb + 1],        c0.y);
    atomicAdd(&colsum[cb + 2],        c0.z); atomicAdd(&colsum[cb + 3],        c0.w);
    atomicAdd(&colsum[1024 + cb + 0], c1.x); atomicAdd(&colsum[1024 + cb + 1], c1.y);
    atomicAdd(&colsum[1024 + cb + 2], c1.z); atomicAdd(&colsum[1024 + cb + 3], c1.w);
    atomicAdd(&colsum[2048 + cb + 0], c2.x); atomicAdd(&colsum[2048 + cb + 1], c2.y);
    atomicAdd(&colsum[2048 + cb + 2], c2.z); atomicAdd(&colsum[2048 + cb + 3], c2.w);
    atomicAdd(&colsum[3072 + cb + 0], c3.x); atomicAdd(&colsum[3072 + cb + 1], c3.y);
    atomicAdd(&colsum[3072 + cb + 2], c3.z); atomicAdd(&colsum[3072 + cb + 3], c3.w);
}

// out = x + best; 1-sync shuffle prologue, round-12 streaming structure
__global__ __launch_bounds__(256) void k_add_fused(
        const float* __restrict__ x,
        const float* __restrict__ inertia, const float* __restrict__ cog,
        const float* __restrict__ soc,
        const float* __restrict__ pos, const float* __restrict__ vel,
        const float* __restrict__ pbp, const float* __restrict__ pbf,
        const float* __restrict__ gbp, const float* __restrict__ gbf,
        const float* __restrict__ r1, const float* __restrict__ r2,
        const float* __restrict__ colsum, const float* __restrict__ blocknorm,
        float* __restrict__ out) {
    const int tid  = threadIdx.x;
    const int lane = tid & 63;
    const int wv   = tid >> 6;
    const size_t base = (size_t)blockIdx.x * 256 + tid;   // float4 idx
    const float4* x4 = (const float4*)x;
    float4* o4 = (float4*)out;

    // issue the 4 x reads early; prologue latency hides under them
    float4 xv0 = x4[base];
    float4 xv1 = x4[base + 1048576];
    float4 xv2 = x4[base + 2 * 1048576];
    float4 xv3 = x4[base + 3 * 1048576];

    __shared__ double wsumS[4];
    __shared__ unsigned long long pmaxS[4];

    // ---- 1-sync prologue: fitness-sum and pbf-argmax reduced in parallel ----
    double d = (double)blocknorm[tid] + (double)blocknorm[tid + 256];
    float p0 = pbf[tid], p1 = pbf[tid + 256];
    // pack: orderable(value)<<32 | (511-idx)  => u64 max == (max val, min idx)
    unsigned long long k0 = ((unsigned long long)ford(p0) << 32) | (unsigned)(511 - tid);
    unsigned long long k1 = ((unsigned long long)ford(p1) << 32) | (unsigned)(255 - tid);
    unsigned long long pm = (k1 > k0) ? k1 : k0;
    #pragma unroll
    for (int m = 1; m <= 32; m <<= 1) {
        d += __shfl_xor(d, m);
        unsigned long long o = __shfl_xor(pm, m);
        pm = (o > pm) ? o : pm;
    }
    if (lane == 0) { wsumS[wv] = d; pmaxS[wv] = pm; }
    __syncthreads();
    const double tot = wsumS[0] + wsumS[1] + wsumS[2] + wsumS[3];
    unsigned long long pa = (pmaxS[0] > pmaxS[1]) ? pmaxS[0] : pmaxS[1];
    unsigned long long pb_ = (pmaxS[2] > pmaxS[3]) ? pmaxS[2] : pmaxS[3];
    unsigned long long pmax = (pa > pb_) ? pa : pb_;
    const float fitness = (float)(-tot / (double)BSZ);
    // vals[i]=max(fitness,pbf[i]) => istar = fitness>=max(pbf) ? 0 : argmax(pbf)
    int istar = 511 - (int)(pmax & 0xFFFFFFFFull);
    if (ford(fitness) >= (unsigned)(pmax >> 32)) istar = 0;

    const bool  imp  = fitness > pbf[istar];
    const bool  gimp = fitness > gbf[0];
    const float w    = inertia[0];
    const float a1   = cog[0] * r1[istar];
    const float a2   = soc[0] * r2[istar];

    // ---- per-thread best4 for its (fixed) column group ----
    const int g = (int)(base & 1023);
    const float4 cs = ((const float4*)colsum)[g];
    const float4 p  = ((const float4*)(pos + (size_t)istar * HSZ))[g];
    const float4 vv = ((const float4*)(vel + (size_t)istar * HSZ))[g];
    const float4 pb = ((const float4*)(pbp + (size_t)istar * HSZ))[g];
    const float4 gb = ((const float4*)gbp)[g];
    const float inv = 1.0f / (float)BSZ;

    float4 bst;
    {
        float pbx = imp ? cs.x * inv : pb.x, gbx = gimp ? cs.x * inv : gb.x;
        float pby = imp ? cs.y * inv : pb.y, gby = gimp ? cs.y * inv : gb.y;
        float pbz = imp ? cs.z * inv : pb.z, gbz = gimp ? cs.z * inv : gb.z;
        float pbw = imp ? cs.w * inv : pb.w, gbw = gimp ? cs.w * inv : gb.w;
        bst.x = p.x + w * vv.x + a1 * (pbx - p.x) + a2 * (gbx - p.x);
        bst.y = p.y + w * vv.y + a1 * (pby - p.y) + a2 * (gby - p.y);
        bst.z = p.z + w * vv.z + a1 * (pbz - p.z) + a2 * (gbz - p.z);
        bst.w = p.w + w * vv.w + a1 * (pbw - p.w) + a2 * (gbw - p.w);
    }

    float4 o0, o1, o2, o3;
    o0.x = xv0.x + bst.x; o0.y = xv0.y + bst.y; o0.z = xv0.z + bst.z; o0.w = xv0.w + bst.w;
    o1.x = xv1.x + bst.x; o1.y = xv1.y + bst.y; o1.z = xv1.z + bst.z; o1.w = xv1.w + bst.w;
    o2.x = xv2.x + bst.x; o2.y = xv2.y + bst.y; o2.z = xv2.z + bst.z; o2.w = xv2.w + bst.w;
    o3.x = xv3.x + bst.x; o3.y = xv3.y + bst.y; o3.z = xv3.z + bst.z; o3.w = xv3.w + bst.w;
    o4[base]               = o0;
    o4[base + 1048576]     = o1;
    o4[base + 2 * 1048576] = o2;
    o4[base + 3 * 1048576] = o3;
}

// ---------------- fallback path (needs only ~33 KB ws) ----------------
__global__ __launch_bounds__(256) void f_reduce(const float* __restrict__ x,
                                                float* __restrict__ colsum,
                                                double* __restrict__ normsum,
                                                int rows_per_block) {
    const int tid = threadIdx.x;
    const int r0 = blockIdx.x * rows_per_block;
    float4 c0 = {0,0,0,0}, c1 = {0,0,0,0}, c2 = {0,0,0,0}, c3 = {0,0,0,0};
    __shared__ float wavepart[4];
    double normacc = 0.0;
    for (int r = 0; r < rows_per_block; ++r) {
        const float4* row = (const float4*)(x + (size_t)(r0 + r) * HSZ);
        float4 a = row[tid], b = row[256 + tid], c = row[512 + tid], d = row[768 + tid];
        c0.x += a.x; c0.y += a.y; c0.z += a.z; c0.w += a.w;
        c1.x += b.x; c1.y += b.y; c1.z += b.z; c1.w += b.w;
        c2.x += c.x; c2.y += c.y; c2.z += c.z; c2.w += c.w;
        c3.x += d.x; c3.y += d.y; c3.z += d.z; c3.w += d.w;
        float sq = a.x*a.x + a.y*a.y + a.z*a.z + a.w*a.w
                 + b.x*b.x + b.y*b.y + b.z*b.z + b.w*b.w
                 + c.x*c.x + c.y*c.y + c.z*c.z + c.w*c.w
                 + d.x*d.x + d.y*d.y + d.z*d.z + d.w*d.w;
        #pragma unroll
        for (int m = 1; m <= 32; m <<= 1) sq += __shfl_xor(sq, m);
        if ((tid & 63) == 0) wavepart[tid >> 6] = sq;
        __syncthreads();
        if (tid == 0) {
            float tot = wavepart[0] + wavepart[1] + wavepart[2] + wavepart[3];
            normacc += sqrt((double)tot);
        }
        __syncthreads();
    }
    if (tid == 0) atomicAdd(normsum, normacc);
    const int cb = 4 * tid;
    atomicAdd(&colsum[cb + 0], c0.x); atomicAdd(&colsum[cb + 1], c0.y);
    atomicAdd(&colsum[cb + 2], c0.z); atomicAdd(&colsum[cb + 3], c0.w);
    atomicAdd(&colsum[1024 + cb + 0], c1.x); atomicAdd(&colsum[1024 + cb + 1], c1.y);
    atomicAdd(&colsum[1024 + cb + 2], c1.z); atomicAdd(&colsum[1024 + cb + 3], c1.w);
    atomicAdd(&colsum[2048 + cb + 0], c2.x); atomicAdd(&colsum[2048 + cb + 1], c2.y);
    atomicAdd(&colsum[2048 + cb + 2], c2.z); atomicAdd(&colsum[2048 + cb + 3], c2.w);
    atomicAdd(&colsum[3072 + cb + 0], c3.x); atomicAdd(&colsum[3072 + cb + 1], c3.y);
    atomicAdd(&colsum[3072 + cb + 2], c3.z); atomicAdd(&colsum[3072 + cb + 3], c3.w);
}

__global__ __launch_bounds__(512) void f_update(
        const float* __restrict__ inertia, const float* __restrict__ cog,
        const float* __restrict__ soc,
        const float* __restrict__ pos, const float* __restrict__ vel,
        const float* __restrict__ pbp, const float* __restrict__ pbf,
        const float* __restrict__ gbp, const float* __restrict__ gbf,
        const float* __restrict__ r1, const float* __restrict__ r2,
        const float* __restrict__ colsum, const double* __restrict__ normsum,
        float* __restrict__ best) {
    const int tid = threadIdx.x;
    __shared__ float vals[PSZ];
    __shared__ int idxs[PSZ];
    const float fitness = (float)(-(*normsum) / (double)BSZ);
    float v = pbf[tid];
    vals[tid] = (fitness > v) ? fitness : v;
    idxs[tid] = tid;
    __syncthreads();
    for (int s = PSZ / 2; s > 0; s >>= 1) {
        if (tid < s) {
            float vo = vals[tid + s]; int io = idxs[tid + s];
            float vm = vals[tid];     int im = idxs[tid];
            if (vo > vm || (vo == vm && io < im)) { vals[tid] = vo; idxs[tid] = io; }
        }
        __syncthreads();
    }
    const int istar = idxs[0];
    const bool  imp  = fitness > pbf[istar];
    const bool  gimp = fitness > gbf[0];
    const float w    = inertia[0], cw = cog[0], sw = soc[0];
    const float r1v  = r1[istar], r2v = r2[istar];
    const float* posr = pos + (size_t)istar * HSZ;
    const float* velr = vel + (size_t)istar * HSZ;
    const float* pbpr = pbp + (size_t)istar * HSZ;
    for (int h = tid; h < HSZ; h += 512) {
        float xm = colsum[h] * (1.0f / (float)BSZ);
        float p  = posr[h];
        float pb = imp  ? xm : pbpr[h];
        float gb = gimp ? xm : gbp[h];
        float vn = w * velr[h] + cw * r1v * (pb - p) + sw * r2v * (gb - p);
        best[h] = p + vn;
    }
}

__global__ __launch_bounds__(256) void f_add(const float* __restrict__ x,
                                             const float* __restrict__ best,
                                             float* __restrict__ out) {
    const size_t n4 = (size_t)BSZ * HSZ / 4;
    const float4* x4 = (const float4*)x;
    const float4* b4 = (const float4*)best;
    float4* o4 = (float4*)out;
    const size_t stride = (size_t)gridDim.x * blockDim.x;
    for (size_t k = (size_t)blockIdx.x * blockDim.x + threadIdx.x; k < n4; k += stride) {
        float4 xv = x4[k];
        float4 bv = b4[k & (HSZ / 4 - 1)];
        float4 ov;
        ov.x = xv.x + bv.x; ov.y = xv.y + bv.y;
        ov.z = xv.z + bv.z; ov.w = xv.w + bv.w;
        o4[k] = ov;
    }
}

extern "C" void kernel_launch(void* const* d_in, const int* in_sizes, int n_in,
                              void* d_out, int out_size, void* d_ws, size_t ws_size,
                              hipStream_t stream) {
    const float* x       = (const float*)d_in[0];
    const float* inertia = (const float*)d_in[1];
    const float* cog     = (const float*)d_in[2];
    const float* soc     = (const float*)d_in[3];
    const float* pos     = (const float*)d_in[4];
    const float* vel     = (const float*)d_in[5];
    const float* pbp     = (const float*)d_in[6];
    const float* pbf     = (const float*)d_in[7];
    const float* gbp     = (const float*)d_in[8];
    const float* gbf     = (const float*)d_in[9];
    const float* r1      = (const float*)d_in[10];
    const float* r2      = (const float*)d_in[11];
    float* out = (float*)d_out;
    char* ws = (char*)d_ws;

    if (ws_size >= WS_NEEDED) {
        float* colsum    = (float*)ws;
        float* blocknorm = (float*)(ws + 16384);

        (void)hipMemsetAsync(colsum, 0, HSZ * sizeof(float), stream);
        k1_reduce<<<NB1, 256, 0, stream>>>(x, colsum, blocknorm);
        k_add_fused<<<4096, 256, 0, stream>>>(x, inertia, cog, soc, pos, vel,
                                              pbp, pbf, gbp, gbf, r1, r2,
                                              colsum, blocknorm, out);
    } else {
        float*  colsum  = (float*)ws;
        double* normsum = (double*)(ws + 16384);
        float*  best    = (float*)(ws + 16416);
        (void)hipMemsetAsync(ws, 0, 16392, stream);
        f_reduce<<<256, 256, 0, stream>>>(x, colsum, normsum, BSZ / 256);
        f_update<<<1, PSZ, 0, stream>>>(inertia, cog, soc, pos, vel, pbp, pbf,
                                        gbp, gbf, r1, r2, colsum, normsum, best);
        f_add<<<2048, 256, 0, stream>>>(x, best, out);
    }
}

// Round 14
// 48.141 us; speedup vs baseline: 2.1855x; 2.1855x over previous
//
#include <hip/hip_runtime.h>

#define HSZ 4096
#define BSZ 4096
#define PSZ 512
#define NB1 512    // k1 blocks, 8 rows each

// ws layout (fast path):
// [0, 8388608)             colpartial float[512][4096]
// [8388608, 8390656)       blocknorm  float[512]
// [8390656, 8407040)       colsum     float[4096]
// [8407040, 8423424)       best       float[4096]   (fallback only)
#define WS_NEEDED 8423424ull

__device__ __forceinline__ unsigned ford(float f) {
    unsigned b = __float_as_uint(f);
    return b ^ ((b & 0x80000000u) ? 0xFFFFFFFFu : 0x80000000u);
}

__global__ __launch_bounds__(256, 2) void k1_reduce(const float* __restrict__ x,
                                                    float* __restrict__ colpartial,
                                                    float* __restrict__ blocknorm,
                                                    float* __restrict__ colsum) {
    const int tid = threadIdx.x;
    const int b = blockIdx.x;

    // block 0 zeroes colsum for this call (replaces memset dispatch)
    if (b == 0) {
        float4 z = {0, 0, 0, 0};
        #pragma unroll
        for (int i = 0; i < 4; ++i) ((float4*)colsum)[tid + 256 * i] = z;
    }

    const int r0 = b * 8;
    float4 c0 = {0,0,0,0}, c1 = {0,0,0,0}, c2 = {0,0,0,0}, c3 = {0,0,0,0};
    __shared__ float sq[8][256];
    __shared__ float norm8[8];

    #pragma unroll
    for (int r = 0; r < 8; ++r) {
        const float4* row = (const float4*)(x + (size_t)(r0 + r) * HSZ);
        float4 a = row[tid];
        float4 e = row[256 + tid];
        float4 c = row[512 + tid];
        float4 d = row[768 + tid];
        c0.x += a.x; c0.y += a.y; c0.z += a.z; c0.w += a.w;
        c1.x += e.x; c1.y += e.y; c1.z += e.z; c1.w += e.w;
        c2.x += c.x; c2.y += c.y; c2.z += c.z; c2.w += c.w;
        c3.x += d.x; c3.y += d.y; c3.z += d.z; c3.w += d.w;
        sq[r][tid] = a.x*a.x + a.y*a.y + a.z*a.z + a.w*a.w
                   + e.x*e.x + e.y*e.y + e.z*e.z + e.w*e.w
                   + c.x*c.x + c.y*c.y + c.z*c.z + c.w*c.w
                   + d.x*d.x + d.y*d.y + d.z*d.z + d.w*d.w;
    }
    __syncthreads();
    {
        const int w = tid >> 6;
        const int l = tid & 63;
        #pragma unroll
        for (int rr = 2 * w; rr <= 2 * w + 1; ++rr) {
            float s = sq[rr][l] + sq[rr][64 + l] + sq[rr][128 + l] + sq[rr][192 + l];
            #pragma unroll
            for (int m = 1; m <= 32; m <<= 1) s += __shfl_xor(s, m);
            if (l == 0) norm8[rr] = sqrtf(s);
        }
    }
    __syncthreads();
    if (tid == 0) {
        float s = 0.f;
        #pragma unroll
        for (int i = 0; i < 8; ++i) s += norm8[i];
        blocknorm[b] = s;
    }

    float4* cp = (float4*)(colpartial + (size_t)b * HSZ);
    cp[tid]       = c0;
    cp[256 + tid] = c1;
    cp[512 + tid] = c2;
    cp[768 + tid] = c3;
}

// colsum over 512 slabs: float4 loads, independent accumulators
__global__ __launch_bounds__(256) void k2_colsum(const float* __restrict__ colpartial,
                                                 float* __restrict__ colsum) {
    const int id  = blockIdx.x * 256 + threadIdx.x;   // [0, 65536)
    const int g   = id & 1023;                        // float4 col-group
    const int seg = id >> 10;                         // 0..63 (8 slabs each)
    const float4* cp4 = (const float4*)colpartial;
    const size_t base = (size_t)seg * 8 * 1024 + g;   // slab seg*8, group g

    float4 a0 = {0,0,0,0}, a1 = {0,0,0,0}, a2 = {0,0,0,0}, a3 = {0,0,0,0};
    #pragma unroll
    for (int k = 0; k < 2; ++k) {
        float4 v0 = cp4[base + (size_t)(4*k + 0) * 1024];
        float4 v1 = cp4[base + (size_t)(4*k + 1) * 1024];
        float4 v2 = cp4[base + (size_t)(4*k + 2) * 1024];
        float4 v3 = cp4[base + (size_t)(4*k + 3) * 1024];
        a0.x += v0.x; a0.y += v0.y; a0.z += v0.z; a0.w += v0.w;
        a1.x += v1.x; a1.y += v1.y; a1.z += v1.z; a1.w += v1.w;
        a2.x += v2.x; a2.y += v2.y; a2.z += v2.z; a2.w += v2.w;
        a3.x += v3.x; a3.y += v3.y; a3.z += v3.z; a3.w += v3.w;
    }
    float sx = a0.x + a1.x + a2.x + a3.x;
    float sy = a0.y + a1.y + a2.y + a3.y;
    float sz = a0.z + a1.z + a2.z + a3.z;
    float sw = a0.w + a1.w + a2.w + a3.w;
    float* c = &colsum[4 * g];
    atomicAdd(&c[0], sx);
    atomicAdd(&c[1], sy);
    atomicAdd(&c[2], sz);
    atomicAdd(&c[3], sw);      // 64-way contention spread over 4096 addrs
}

// out = x + best; 1-sync shuffle prologue, round-9 streaming structure
__global__ __launch_bounds__(256) void k_add_fused(
        const float* __restrict__ x,
        const float* __restrict__ inertia, const float* __restrict__ cog,
        const float* __restrict__ soc,
        const float* __restrict__ pos, const float* __restrict__ vel,
        const float* __restrict__ pbp, const float* __restrict__ pbf,
        const float* __restrict__ gbp, const float* __restrict__ gbf,
        const float* __restrict__ r1, const float* __restrict__ r2,
        const float* __restrict__ colsum, const float* __restrict__ blocknorm,
        float* __restrict__ out) {
    const int tid  = threadIdx.x;
    const int lane = tid & 63;
    const int wv   = tid >> 6;
    const size_t base = (size_t)blockIdx.x * 256 + tid;   // float4 idx
    const float4* x4 = (const float4*)x;
    float4* o4 = (float4*)out;

    // issue the 4 x reads early; prologue latency hides under them
    float4 xv0 = x4[base];
    float4 xv1 = x4[base + 1048576];
    float4 xv2 = x4[base + 2 * 1048576];
    float4 xv3 = x4[base + 3 * 1048576];

    __shared__ double wsumS[4];
    __shared__ unsigned long long pmaxS[4];

    // ---- 1-sync prologue: fitness-sum and pbf-argmax reduced in parallel ----
    double d = (double)blocknorm[tid] + (double)blocknorm[tid + 256];
    float p0 = pbf[tid], p1 = pbf[tid + 256];
    // pack: orderable(value)<<32 | (511-idx)  => u64 max == (max val, min idx)
    unsigned long long k0 = ((unsigned long long)ford(p0) << 32) | (unsigned)(511 - tid);
    unsigned long long k1 = ((unsigned long long)ford(p1) << 32) | (unsigned)(255 - tid);
    unsigned long long pm = (k1 > k0) ? k1 : k0;
    #pragma unroll
    for (int m = 1; m <= 32; m <<= 1) {
        d += __shfl_xor(d, m);
        unsigned long long o = __shfl_xor(pm, m);
        pm = (o > pm) ? o : pm;
    }
    if (lane == 0) { wsumS[wv] = d; pmaxS[wv] = pm; }
    __syncthreads();
    const double tot = wsumS[0] + wsumS[1] + wsumS[2] + wsumS[3];
    unsigned long long pa = (pmaxS[0] > pmaxS[1]) ? pmaxS[0] : pmaxS[1];
    unsigned long long pb_ = (pmaxS[2] > pmaxS[3]) ? pmaxS[2] : pmaxS[3];
    unsigned long long pmax = (pa > pb_) ? pa : pb_;
    const float fitness = (float)(-tot / (double)BSZ);
    // vals[i]=max(fitness,pbf[i]) => istar = fitness>=max(pbf) ? 0 : argmax(pbf)
    int istar = 511 - (int)(pmax & 0xFFFFFFFFull);
    if (ford(fitness) >= (unsigned)(pmax >> 32)) istar = 0;

    const bool  imp  = fitness > pbf[istar];
    const bool  gimp = fitness > gbf[0];
    const float w    = inertia[0];
    const float a1   = cog[0] * r1[istar];
    const float a2   = soc[0] * r2[istar];

    // ---- per-thread best4 for its (fixed) column group ----
    const int g = (int)(base & 1023);
    const float4 cs = ((const float4*)colsum)[g];
    const float4 p  = ((const float4*)(pos + (size_t)istar * HSZ))[g];
    const float4 vv = ((const float4*)(vel + (size_t)istar * HSZ))[g];
    const float4 pb = ((const float4*)(pbp + (size_t)istar * HSZ))[g];
    const float4 gb = ((const float4*)gbp)[g];
    const float inv = 1.0f / (float)BSZ;

    float4 bst;
    {
        float pbx = imp ? cs.x * inv : pb.x, gbx = gimp ? cs.x * inv : gb.x;
        float pby = imp ? cs.y * inv : pb.y, gby = gimp ? cs.y * inv : gb.y;
        float pbz = imp ? cs.z * inv : pb.z, gbz = gimp ? cs.z * inv : gb.z;
        float pbw = imp ? cs.w * inv : pb.w, gbw = gimp ? cs.w * inv : gb.w;
        bst.x = p.x + w * vv.x + a1 * (pbx - p.x) + a2 * (gbx - p.x);
        bst.y = p.y + w * vv.y + a1 * (pby - p.y) + a2 * (gby - p.y);
        bst.z = p.z + w * vv.z + a1 * (pbz - p.z) + a2 * (gbz - p.z);
        bst.w = p.w + w * vv.w + a1 * (pbw - p.w) + a2 * (gbw - p.w);
    }

    float4 o0, o1, o2, o3;
    o0.x = xv0.x + bst.x; o0.y = xv0.y + bst.y; o0.z = xv0.z + bst.z; o0.w = xv0.w + bst.w;
    o1.x = xv1.x + bst.x; o1.y = xv1.y + bst.y; o1.z = xv1.z + bst.z; o1.w = xv1.w + bst.w;
    o2.x = xv2.x + bst.x; o2.y = xv2.y + bst.y; o2.z = xv2.z + bst.z; o2.w = xv2.w + bst.w;
    o3.x = xv3.x + bst.x; o3.y = xv3.y + bst.y; o3.z = xv3.z + bst.z; o3.w = xv3.w + bst.w;
    o4[base]               = o0;
    o4[base + 1048576]     = o1;
    o4[base + 2 * 1048576] = o2;
    o4[base + 3 * 1048576] = o3;
}

// ---------------- fallback path (needs only ~33 KB ws) ----------------
__global__ __launch_bounds__(256) void f_reduce(const float* __restrict__ x,
                                                float* __restrict__ colsum,
                                                double* __restrict__ normsum,
                                                int rows_per_block) {
    const int tid = threadIdx.x;
    const int r0 = blockIdx.x * rows_per_block;
    float4 c0 = {0,0,0,0}, c1 = {0,0,0,0}, c2 = {0,0,0,0}, c3 = {0,0,0,0};
    __shared__ float wavepart[4];
    double normacc = 0.0;
    for (int r = 0; r < rows_per_block; ++r) {
        const float4* row = (const float4*)(x + (size_t)(r0 + r) * HSZ);
        float4 a = row[tid], b = row[256 + tid], c = row[512 + tid], d = row[768 + tid];
        c0.x += a.x; c0.y += a.y; c0.z += a.z; c0.w += a.w;
        c1.x += b.x; c1.y += b.y; c1.z += b.z; c1.w += b.w;
        c2.x += c.x; c2.y += c.y; c2.z += c.z; c2.w += c.w;
        c3.x += d.x; c3.y += d.y; c3.z += d.z; c3.w += d.w;
        float sq = a.x*a.x + a.y*a.y + a.z*a.z + a.w*a.w
                 + b.x*b.x + b.y*b.y + b.z*b.z + b.w*b.w
                 + c.x*c.x + c.y*c.y + c.z*c.z + c.w*c.w
                 + d.x*d.x + d.y*d.y + d.z*d.z + d.w*d.w;
        #pragma unroll
        for (int m = 1; m <= 32; m <<= 1) sq += __shfl_xor(sq, m);
        if ((tid & 63) == 0) wavepart[tid >> 6] = sq;
        __syncthreads();
        if (tid == 0) {
            float tot = wavepart[0] + wavepart[1] + wavepart[2] + wavepart[3];
            normacc += sqrt((double)tot);
        }
        __syncthreads();
    }
    if (tid == 0) atomicAdd(normsum, normacc);
    const int cb = 4 * tid;
    atomicAdd(&colsum[cb + 0], c0.x); atomicAdd(&colsum[cb + 1], c0.y);
    atomicAdd(&colsum[cb + 2], c0.z); atomicAdd(&colsum[cb + 3], c0.w);
    atomicAdd(&colsum[1024 + cb + 0], c1.x); atomicAdd(&colsum[1024 + cb + 1], c1.y);
    atomicAdd(&colsum[1024 + cb + 2], c1.z); atomicAdd(&colsum[1024 + cb + 3], c1.w);
    atomicAdd(&colsum[2048 + cb + 0], c2.x); atomicAdd(&colsum[2048 + cb + 1], c2.y);
    atomicAdd(&colsum[2048 + cb + 2], c2.z); atomicAdd(&colsum[2048 + cb + 3], c2.w);
    atomicAdd(&colsum[3072 + cb + 0], c3.x); atomicAdd(&colsum[3072 + cb + 1], c3.y);
    atomicAdd(&colsum[3072 + cb + 2], c3.z); atomicAdd(&colsum[3072 + cb + 3], c3.w);
}

__global__ __launch_bounds__(512) void f_update(
        const float* __restrict__ inertia, const float* __restrict__ cog,
        const float* __restrict__ soc,
        const float* __restrict__ pos, const float* __restrict__ vel,
        const float* __restrict__ pbp, const float* __restrict__ pbf,
        const float* __restrict__ gbp, const float* __restrict__ gbf,
        const float* __restrict__ r1, const float* __restrict__ r2,
        const float* __restrict__ colsum, const double* __restrict__ normsum,
        float* __restrict__ best) {
    const int tid = threadIdx.x;
    __shared__ float vals[PSZ];
    __shared__ int idxs[PSZ];
    const float fitness = (float)(-(*normsum) / (double)BSZ);
    float v = pbf[tid];
    vals[tid] = (fitness > v) ? fitness : v;
    idxs[tid] = tid;
    __syncthreads();
    for (int s = PSZ / 2; s > 0; s >>= 1) {
        if (tid < s) {
            float vo = vals[tid + s]; int io = idxs[tid + s];
            float vm = vals[tid];     int im = idxs[tid];
            if (vo > vm || (vo == vm && io < im)) { vals[tid] = vo; idxs[tid] = io; }
        }
        __syncthreads();
    }
    const int istar = idxs[0];
    const bool  imp  = fitness > pbf[istar];
    const bool  gimp = fitness > gbf[0];
    const float w    = inertia[0], cw = cog[0], sw = soc[0];
    const float r1v  = r1[istar], r2v = r2[istar];
    const float* posr = pos + (size_t)istar * HSZ;
    const float* velr = vel + (size_t)istar * HSZ;
    const float* pbpr = pbp + (size_t)istar * HSZ;
    for (int h = tid; h < HSZ; h += 512) {
        float xm = colsum[h] * (1.0f / (float)BSZ);
        float p  = posr[h];
        float pb = imp  ? xm : pbpr[h];
        float gb = gimp ? xm : gbp[h];
        float vn = w * velr[h] + cw * r1v * (pb - p) + sw * r2v * (gb - p);
        best[h] = p + vn;
    }
}

__global__ __launch_bounds__(256) void f_add(const float* __restrict__ x,
                                             const float* __restrict__ best,
                                             float* __restrict__ out) {
    const size_t n4 = (size_t)BSZ * HSZ / 4;
    const float4* x4 = (const float4*)x;
    const float4* b4 = (const float4*)best;
    float4* o4 = (float4*)out;
    const size_t stride = (size_t)gridDim.x * blockDim.x;
    for (size_t k = (size_t)blockIdx.x * blockDim.x + threadIdx.x; k < n4; k += stride) {
        float4 xv = x4[k];
        float4 bv = b4[k & (HSZ / 4 - 1)];
        float4 ov;
        ov.x = xv.x + bv.x; ov.y = xv.y + bv.y;
        ov.z = xv.z + bv.z; ov.w = xv.w + bv.w;
        o4[k] = ov;
    }
}

extern "C" void kernel_launch(void* const* d_in, const int* in_sizes, int n_in,
                              void* d_out, int out_size, void* d_ws, size_t ws_size,
                              hipStream_t stream) {
    const float* x       = (const float*)d_in[0];
    const float* inertia = (const float*)d_in[1];
    const float* cog     = (const float*)d_in[2];
    const float* soc     = (const float*)d_in[3];
    const float* pos     = (const float*)d_in[4];
    const float* vel     = (const float*)d_in[5];
    const float* pbp     = (const float*)d_in[6];
    const float* pbf     = (const float*)d_in[7];
    const float* gbp     = (const float*)d_in[8];
    const float* gbf     = (const float*)d_in[9];
    const float* r1      = (const float*)d_in[10];
    const float* r2      = (const float*)d_in[11];
    float* out = (float*)d_out;
    char* ws = (char*)d_ws;

    if (ws_size >= WS_NEEDED) {
        float* colpartial = (float*)ws;
        float* blocknorm  = (float*)(ws + 8388608);
        float* colsum     = (float*)(ws + 8390656);

        k1_reduce<<<NB1, 256, 0, stream>>>(x, colpartial, blocknorm, colsum);
        k2_colsum<<<256, 256, 0, stream>>>(colpartial, colsum);
        k_add_fused<<<4096, 256, 0, stream>>>(x, inertia, cog, soc, pos, vel,
                                              pbp, pbf, gbp, gbf, r1, r2,
                                              colsum, blocknorm, out);
    } else {
        float*  colsum  = (float*)ws;
        double* normsum = (double*)(ws + 16384);
        float*  best    = (float*)(ws + 16416);
        (void)hipMemsetAsync(ws, 0, 16392, stream);
        f_reduce<<<256, 256, 0, stream>>>(x, colsum, normsum, BSZ / 256);
        f_update<<<1, PSZ, 0, stream>>>(inertia, cog, soc, pos, vel, pbp, pbf,
                                        gbp, gbf, r1, r2, colsum, normsum, best);
        f_add<<<2048, 256, 0, stream>>>(x, best, out);
    }
}